// Round 1
// baseline (187.758 us; speedup 1.0000x reference)
//
#include <hip/hip_runtime.h>
#include <hip/hip_bf16.h>

// Problem constants
#define B    32
#define P    576     // 24*24 patches
#define D    768
#define K1   17      // K+1 prototypes
#define KFG  16
#define C    200
#define LN_EPS 1e-6f

// ---------------- k0: p_sq[k] = sum_d proto[k][d]^2 ----------------
__global__ __launch_bounds__(64) void k_psq(const float* __restrict__ proto,
                                            float* __restrict__ psq) {
    int k = blockIdx.x;
    int lane = threadIdx.x;
    float s = 0.f;
    #pragma unroll
    for (int j = 0; j < 12; ++j) {
        float v = proto[k * D + lane + j * 64];
        s += v * v;
    }
    #pragma unroll
    for (int o = 1; o < 64; o <<= 1) s += __shfl_xor(s, o, 64);
    if (lane == 0) psq[k] = s;
}

// ---------------- k1a: partial dots xp over a d-quarter ----------------
// grid (9 tiles, 4 d-quarters, 32 batches), block 256.
// LDS x-tile: 64 patches x 192 floats, pitch 194 (dword pitch % 32 == 2 -> 2-way, free)
__global__ __launch_bounds__(256) void k_dots(const float* __restrict__ x,
                                              const float* __restrict__ proto,
                                              float* __restrict__ xpp) {
    __shared__ float xs[64 * 194];
    const int tile = blockIdx.x, dq = blockIdx.y, b = blockIdx.z;
    const int t = threadIdx.x;

    // ---- stage: each thread loads 48 contiguous floats of one patch-quarter ----
    {
        const int p_loc = t >> 2, q = t & 3;
        const float* src = x + ((b * P + tile * 64 + p_loc) * D) + dq * 192 + q * 48;
        float* dst = xs + p_loc * 194 + q * 48;
        #pragma unroll
        for (int i = 0; i < 12; ++i) {
            float4 v = *(const float4*)(src + i * 4);
            // pitch 194 breaks 16B alignment for odd rows -> two float2 stores
            *(float2*)(dst + i * 4)     = make_float2(v.x, v.y);
            *(float2*)(dst + i * 4 + 2) = make_float2(v.z, v.w);
        }
    }
    __syncthreads();

    // ---- dot phase: lane = patch; wave w handles k in {w, w+4, w+8, w+12} (+16 on w0) ----
    const int lane = t & 63;
    const int wv = __builtin_amdgcn_readfirstlane(t >> 6);   // wave-uniform -> SGPR
    const float* pr0 = proto + (wv)      * D + dq * 192;
    const float* pr1 = proto + (wv + 4)  * D + dq * 192;
    const float* pr2 = proto + (wv + 8)  * D + dq * 192;
    const float* pr3 = proto + (wv + 12) * D + dq * 192;
    const float* pr4 = proto + 16        * D + dq * 192;     // k=16 (only wave 0 writes it)

    float a0 = 0.f, a1 = 0.f, a2 = 0.f, a3 = 0.f, a4 = 0.f;
    const float* xrow = xs + lane * 194;

    for (int c = 0; c < 24; ++c) {
        const int d0 = c * 8;
        float2 r0 = *(const float2*)(xrow + d0);
        float2 r1 = *(const float2*)(xrow + d0 + 2);
        float2 r2 = *(const float2*)(xrow + d0 + 4);
        float2 r3 = *(const float2*)(xrow + d0 + 6);
        float xv[8] = { r0.x, r0.y, r1.x, r1.y, r2.x, r2.y, r3.x, r3.y };
        #pragma unroll
        for (int i = 0; i < 8; ++i) {
            // prototype values are wave-uniform -> scalar loads, FMA w/ SGPR operand
            a0 += xv[i] * pr0[d0 + i];
            a1 += xv[i] * pr1[d0 + i];
            a2 += xv[i] * pr2[d0 + i];
            a3 += xv[i] * pr3[d0 + i];
            a4 += xv[i] * pr4[d0 + i];
        }
    }

    const int pg = tile * 64 + lane;
    float* o = xpp + ((dq * B + b) * K1) * P + pg;
    o[(wv)      * P] = a0;
    o[(wv + 4)  * P] = a1;
    o[(wv + 8)  * P] = a2;
    o[(wv + 12) * P] = a3;
    if (wv == 0) o[16 * P] = a4;
}

// ---------------- k1b: combine partials + softmax; write A and a/576 ----------------
// grid (9, 32), block 64 (one wave, lane = patch)
__global__ __launch_bounds__(64) void k_softmax(const float* __restrict__ xpp,
                                                const float* __restrict__ psq,
                                                float* __restrict__ A_out,
                                                float* __restrict__ a_ws) {
    const int b = blockIdx.y;
    const int p = blockIdx.x * 64 + threadIdx.x;

    float l[K1];
    #pragma unroll
    for (int k = 0; k < K1; ++k) {
        float s = 0.f;
        #pragma unroll
        for (int dq = 0; dq < 4; ++dq)
            s += xpp[((dq * B + b) * K1 + k) * P + p];
        l[k] = 2.f * s - psq[k];          // x_sq cancels in softmax
    }
    float m = l[0];
    #pragma unroll
    for (int k = 1; k < K1; ++k) m = fmaxf(m, l[k]);
    float e[K1]; float sum = 0.f;
    #pragma unroll
    for (int k = 0; k < K1; ++k) { e[k] = __expf(l[k] - m); sum += e[k]; }
    const float inv = 1.f / sum;

    #pragma unroll
    for (int k = 0; k < K1; ++k)
        A_out[(b * K1 + k) * P + p] = e[k] * inv;   // coalesced per k

    const float invP = inv * (1.f / (float)P);
    float* aw = a_ws + (b * P + p) * KFG;
    #pragma unroll
    for (int i = 0; i < 4; ++i) {
        float4 v = make_float4(e[4*i] * invP, e[4*i+1] * invP,
                               e[4*i+2] * invP, e[4*i+3] * invP);
        *(float4*)(aw + 4 * i) = v;
    }
}

// ---------------- k2: v partial pooling over a p-range ----------------
// grid (3 d-chunks of 256, 4 p-splits, 32 b), block 256; thread owns one d.
__global__ __launch_bounds__(256) void k_pool(const float* __restrict__ x,
                                              const float* __restrict__ a_ws,
                                              float* __restrict__ vpart) {
    const int d = blockIdx.x * 256 + threadIdx.x;
    const int ps = blockIdx.y, b = blockIdx.z;

    float acc[KFG];
    #pragma unroll
    for (int k = 0; k < KFG; ++k) acc[k] = 0.f;

    const float* aw = a_ws + (b * P + ps * 144) * KFG;     // wave-uniform rows -> s_load_dwordx16
    const float* xp = x + (b * P + ps * 144) * D + d;

    #pragma unroll 2
    for (int p = 0; p < 144; ++p) {
        float xv = xp[p * D];
        const float* ap = aw + p * KFG;
        #pragma unroll
        for (int k = 0; k < KFG; ++k) acc[k] += ap[k] * xv;
    }
    float* o = vpart + ((ps * B + b) * KFG) * D + d;
    #pragma unroll
    for (int k = 0; k < KFG; ++k) o[k * D] = acc[k];
}

// ---------------- k3: reduce p-splits + LayerNorm ----------------
// grid (16 k, 32 b), block 256; thread owns 3 d's.
__global__ __launch_bounds__(256) void k_ln(const float* __restrict__ vpart,
                                            const float* __restrict__ gamma,
                                            const float* __restrict__ beta,
                                            float* __restrict__ vnorm_out,
                                            float* __restrict__ vT) {
    const int k = blockIdx.x, b = blockIdx.y, t = threadIdx.x;
    const int lane = t & 63, wv = t >> 6;

    float v[3]; float s1 = 0.f, s2 = 0.f;
    #pragma unroll
    for (int j = 0; j < 3; ++j) {
        const int d = t + j * 256;
        float s = 0.f;
        #pragma unroll
        for (int ps = 0; ps < 4; ++ps)
            s += vpart[((ps * B + b) * KFG + k) * D + d];
        v[j] = s; s1 += s; s2 += s * s;
    }
    #pragma unroll
    for (int o = 1; o < 64; o <<= 1) {
        s1 += __shfl_xor(s1, o, 64);
        s2 += __shfl_xor(s2, o, 64);
    }
    __shared__ float r1[4], r2[4];
    if (lane == 0) { r1[wv] = s1; r2[wv] = s2; }
    __syncthreads();
    s1 = r1[0] + r1[1] + r1[2] + r1[3];
    s2 = r2[0] + r2[1] + r2[2] + r2[3];

    const float mean = s1 * (1.f / (float)D);
    const float var  = s2 * (1.f / (float)D) - mean * mean;
    const float rs   = rsqrtf(var + LN_EPS);

    #pragma unroll
    for (int j = 0; j < 3; ++j) {
        const int d = t + j * 256;
        float vn = (v[j] - mean) * rs * gamma[d] + beta[d];
        vnorm_out[(b * KFG + k) * D + d] = vn;
        vT[(b * D + d) * KFG + k] = vn;    // k-contiguous for k4's scalar loads
    }
}

// ---------------- k4: classifier partial GEMV over a d-range ----------------
// grid (8 d-splits of 96, 32 b), block 256; thread = class c (c<200 active).
__global__ __launch_bounds__(256) void k_cls(const float* __restrict__ vT,
                                             const float* __restrict__ W,
                                             float* __restrict__ lpart) {
    const int dq = blockIdx.x, b = blockIdx.y;
    const int c = threadIdx.x;
    const int cc = c < C ? c : (C - 1);     // clamp keeps loads in-bounds

    float acc[KFG];
    #pragma unroll
    for (int k = 0; k < KFG; ++k) acc[k] = 0.f;

    const float* vt = vT + b * D * KFG + dq * 96 * KFG;
    const float* Wp = W + dq * 96 * C + cc;

    #pragma unroll 2
    for (int i = 0; i < 96; ++i) {
        float wl = Wp[i * C];               // coalesced across lanes
        const float* vr = vt + i * KFG;     // wave-uniform -> s_load_dwordx16
        #pragma unroll
        for (int k = 0; k < KFG; ++k) acc[k] += vr[k] * wl;
    }
    if (c < C) {
        float* o = lpart + ((dq * B + b) * KFG) * C + c;
        #pragma unroll
        for (int k = 0; k < KFG; ++k) o[k * C] = acc[k];
    }
}

// ---------------- k5: combine d-splits + bias; logits_parts + logits_agg ----------------
// grid (32 b), block 256; thread = class c.
__global__ __launch_bounds__(256) void k_comb(const float* __restrict__ lpart,
                                              const float* __restrict__ bcls,
                                              float* __restrict__ parts,
                                              float* __restrict__ agg) {
    const int b = blockIdx.x, c = threadIdx.x;
    if (c >= C) return;
    const float bc = bcls[c];
    float s_agg = 0.f;
    #pragma unroll
    for (int k = 0; k < KFG; ++k) {
        float s = bc;
        #pragma unroll
        for (int dq = 0; dq < 8; ++dq)
            s += lpart[((dq * B + b) * KFG + k) * C + c];
        parts[(b * KFG + k) * C + c] = s;
        s_agg += s;
    }
    agg[b * C + c] = s_agg * (1.f / (float)KFG);
}

extern "C" void kernel_launch(void* const* d_in, const int* in_sizes, int n_in,
                              void* d_out, int out_size, void* d_ws, size_t ws_size,
                              hipStream_t stream) {
    const float* x     = (const float*)d_in[0];   // (32,24,24,768)
    const float* proto = (const float*)d_in[1];   // (17,768)
    const float* gamma = (const float*)d_in[2];   // (768)
    const float* beta  = (const float*)d_in[3];   // (768)
    const float* W     = (const float*)d_in[4];   // (768,200)
    const float* bcls  = (const float*)d_in[5];   // (200)

    float* out = (float*)d_out;
    float* A_out     = out;                       // 32*17*576   = 313344
    float* vnorm_out = out + 313344;              // 32*16*768   = 393216
    float* parts_out = out + 706560;              // 32*16*200   = 102400
    float* agg_out   = out + 808960;              // 32*200      = 6400

    float* ws = (float*)d_ws;
    float* psq   = ws;                 // 17            (pad to 32)
    float* xpp   = ws + 32;            // 4*32*17*576   = 1253376
    float* a_ws  = ws + 1253408;       // 32*576*16     = 294912
    float* vpart = ws + 1548320;       // 4*32*16*768   = 1572864
    float* vT    = ws + 3121184;       // 32*768*16     = 393216
    float* lpart = ws + 3514400;       // 8*32*16*200   = 819200  -> end 4333600 floats

    hipLaunchKernelGGL(k_psq,     dim3(K1),        dim3(64),  0, stream, proto, psq);
    hipLaunchKernelGGL(k_dots,    dim3(9, 4, B),   dim3(256), 0, stream, x, proto, xpp);
    hipLaunchKernelGGL(k_softmax, dim3(9, B),      dim3(64),  0, stream, xpp, psq, A_out, a_ws);
    hipLaunchKernelGGL(k_pool,    dim3(3, 4, B),   dim3(256), 0, stream, x, a_ws, vpart);
    hipLaunchKernelGGL(k_ln,      dim3(KFG, B),    dim3(256), 0, stream, vpart, gamma, beta, vnorm_out, vT);
    hipLaunchKernelGGL(k_cls,     dim3(8, B),      dim3(256), 0, stream, vT, W, lpart);
    hipLaunchKernelGGL(k_comb,    dim3(B),         dim3(256), 0, stream, lpart, bcls, parts_out, agg_out);
}

// Round 2
// 179.480 us; speedup vs baseline: 1.0461x; 1.0461x over previous
//
#include <hip/hip_runtime.h>
#include <hip/hip_bf16.h>

// Problem constants
#define B    32
#define P    576     // 24*24 patches
#define D    768
#define K1   17      // K+1 prototypes
#define KFG  16
#define C    200
#define LN_EPS 1e-6f

// ---------------- k0: p_sq[k] = sum_d proto[k][d]^2 ----------------
__global__ __launch_bounds__(64) void k_psq(const float* __restrict__ proto,
                                            float* __restrict__ psq) {
    int k = blockIdx.x;
    int lane = threadIdx.x;
    float s = 0.f;
    #pragma unroll
    for (int j = 0; j < 12; ++j) {
        float v = proto[k * D + lane + j * 64];
        s += v * v;
    }
    #pragma unroll
    for (int o = 1; o < 64; o <<= 1) s += __shfl_xor(s, o, 64);
    if (lane == 0) psq[k] = s;
}

// ---------------- k1: partial dots xp over a d-quarter ----------------
// grid (9 tiles, 4 d-quarters, 32 batches), block 256 (4 waves).
// Prototype chunk lives in LDS; uniform-address ds_read_b128 -> HW broadcast,
// no s_load latency chains, no SGPR pressure.
// LDS: x tile 64x194 (49.7KB) + proto chunk 17x192 (13KB) = 62.7KB -> 2 blocks/CU.
__global__ __launch_bounds__(256) void k_dots(const float* __restrict__ x,
                                              const float* __restrict__ proto,
                                              float* __restrict__ xpp) {
    __shared__ float xs[64 * 194];
    __shared__ float ps[17 * 192];
    const int tile = blockIdx.x, dq = blockIdx.y, b = blockIdx.z;
    const int t = threadIdx.x;

    // stage proto chunk (3264 floats, coalesced in 192-runs)
    for (int i = t; i < 17 * 192; i += 256) {
        int k = i / 192, dcol = i - k * 192;
        ps[i] = proto[k * D + dq * 192 + dcol];
    }
    // stage x tile: thread loads 48 contiguous floats of one patch-quarter
    {
        const int p_loc = t >> 2, q = t & 3;
        const float* src = x + ((size_t)(b * P + tile * 64 + p_loc) * D) + dq * 192 + q * 48;
        float* dst = xs + p_loc * 194 + q * 48;
        #pragma unroll
        for (int i = 0; i < 12; ++i) {
            float4 v = *(const float4*)(src + i * 4);
            // pitch 194 breaks 16B alignment for odd rows -> two float2 stores
            *(float2*)(dst + i * 4)     = make_float2(v.x, v.y);
            *(float2*)(dst + i * 4 + 2) = make_float2(v.z, v.w);
        }
    }
    __syncthreads();

    // lane = patch; wave wv handles k in {wv, wv+4, wv+8, wv+12} (+16 on wave 0)
    const int lane = t & 63;
    const int wv = t >> 6;
    const float* xrow = xs + lane * 194;
    const float* p0 = ps + (wv)      * 192;
    const float* p1 = ps + (wv + 4)  * 192;
    const float* p2 = ps + (wv + 8)  * 192;
    const float* p3 = ps + (wv + 12) * 192;
    const float* p4 = ps + 16        * 192;

    float a0 = 0.f, a1 = 0.f, a2 = 0.f, a3 = 0.f, a4 = 0.f;

    for (int c = 0; c < 24; ++c) {
        const int d0 = c * 8;
        float2 r0 = *(const float2*)(xrow + d0);
        float2 r1 = *(const float2*)(xrow + d0 + 2);
        float2 r2 = *(const float2*)(xrow + d0 + 4);
        float2 r3 = *(const float2*)(xrow + d0 + 6);
        float xv[8] = { r0.x, r0.y, r1.x, r1.y, r2.x, r2.y, r3.x, r3.y };

        // uniform-address LDS reads: broadcast, 2x ds_read_b128 per k
        float4 q0a = *(const float4*)(p0 + d0), q0b = *(const float4*)(p0 + d0 + 4);
        float4 q1a = *(const float4*)(p1 + d0), q1b = *(const float4*)(p1 + d0 + 4);
        float4 q2a = *(const float4*)(p2 + d0), q2b = *(const float4*)(p2 + d0 + 4);
        float4 q3a = *(const float4*)(p3 + d0), q3b = *(const float4*)(p3 + d0 + 4);
        float4 q4a = *(const float4*)(p4 + d0), q4b = *(const float4*)(p4 + d0 + 4);

        a0 += xv[0]*q0a.x + xv[1]*q0a.y + xv[2]*q0a.z + xv[3]*q0a.w
            + xv[4]*q0b.x + xv[5]*q0b.y + xv[6]*q0b.z + xv[7]*q0b.w;
        a1 += xv[0]*q1a.x + xv[1]*q1a.y + xv[2]*q1a.z + xv[3]*q1a.w
            + xv[4]*q1b.x + xv[5]*q1b.y + xv[6]*q1b.z + xv[7]*q1b.w;
        a2 += xv[0]*q2a.x + xv[1]*q2a.y + xv[2]*q2a.z + xv[3]*q2a.w
            + xv[4]*q2b.x + xv[5]*q2b.y + xv[6]*q2b.z + xv[7]*q2b.w;
        a3 += xv[0]*q3a.x + xv[1]*q3a.y + xv[2]*q3a.z + xv[3]*q3a.w
            + xv[4]*q3b.x + xv[5]*q3b.y + xv[6]*q3b.z + xv[7]*q3b.w;
        a4 += xv[0]*q4a.x + xv[1]*q4a.y + xv[2]*q4a.z + xv[3]*q4a.w
            + xv[4]*q4b.x + xv[5]*q4b.y + xv[6]*q4b.z + xv[7]*q4b.w;
    }

    const int pg = tile * 64 + lane;
    float* o = xpp + ((size_t)(dq * B + b) * K1) * P + pg;
    o[(wv)      * P] = a0;
    o[(wv + 4)  * P] = a1;
    o[(wv + 8)  * P] = a2;
    o[(wv + 12) * P] = a3;
    if (wv == 0) o[16 * P] = a4;
}

// ---------------- k2: combine partials + softmax; write A and a/576 ----------------
// grid 72 blocks x 256 threads; thread = flat (b,p) index.
__global__ __launch_bounds__(256) void k_softmax(const float* __restrict__ xpp,
                                                 const float* __restrict__ psq,
                                                 float* __restrict__ A_out,
                                                 float* __restrict__ a_ws) {
    const int g = blockIdx.x * 256 + threadIdx.x;   // 0..18431
    const int b = g / P, p = g - b * P;

    float l[K1];
    #pragma unroll
    for (int k = 0; k < K1; ++k) {
        float s = 0.f;
        #pragma unroll
        for (int dq = 0; dq < 4; ++dq)
            s += xpp[((size_t)(dq * B + b) * K1 + k) * P + p];
        l[k] = 2.f * s - psq[k];          // x_sq cancels in softmax
    }
    float m = l[0];
    #pragma unroll
    for (int k = 1; k < K1; ++k) m = fmaxf(m, l[k]);
    float e[K1]; float sum = 0.f;
    #pragma unroll
    for (int k = 0; k < K1; ++k) { e[k] = __expf(l[k] - m); sum += e[k]; }
    const float inv = 1.f / sum;

    #pragma unroll
    for (int k = 0; k < K1; ++k)
        A_out[(size_t)(b * K1 + k) * P + p] = e[k] * inv;

    const float invP = inv * (1.f / (float)P);
    float* aw = a_ws + (size_t)g * KFG;
    #pragma unroll
    for (int i = 0; i < 4; ++i) {
        float4 v = make_float4(e[4*i] * invP, e[4*i+1] * invP,
                               e[4*i+2] * invP, e[4*i+3] * invP);
        *(float4*)(aw + 4 * i) = v;
    }
}

// ---------------- k3: v partial pooling over a p-range ----------------
// grid (3 d-chunks of 256, 4 p-splits, 32 b), block 256; thread owns one d.
// a-rows staged to LDS once; uniform ds_read_b128 broadcast in the loop.
__global__ __launch_bounds__(256) void k_pool(const float* __restrict__ x,
                                              const float* __restrict__ a_ws,
                                              float* __restrict__ vpart) {
    __shared__ float as_[144 * 16];   // 9.2 KB
    const int dc = blockIdx.x, psl = blockIdx.y, b = blockIdx.z;
    const int t = threadIdx.x;

    const float* asrc = a_ws + ((size_t)b * P + psl * 144) * KFG;
    for (int i = t; i < 144 * 16; i += 256) as_[i] = asrc[i];
    __syncthreads();

    const int d = dc * 256 + t;
    const float* xp = x + ((size_t)b * P + psl * 144) * D + d;

    float acc[KFG];
    #pragma unroll
    for (int k = 0; k < KFG; ++k) acc[k] = 0.f;

    #pragma unroll 2
    for (int p = 0; p < 144; ++p) {
        float xv = xp[(size_t)p * D];
        float4 A0 = *(const float4*)(as_ + p * 16);
        float4 A1 = *(const float4*)(as_ + p * 16 + 4);
        float4 A2 = *(const float4*)(as_ + p * 16 + 8);
        float4 A3 = *(const float4*)(as_ + p * 16 + 12);
        acc[0]  += A0.x * xv; acc[1]  += A0.y * xv; acc[2]  += A0.z * xv; acc[3]  += A0.w * xv;
        acc[4]  += A1.x * xv; acc[5]  += A1.y * xv; acc[6]  += A1.z * xv; acc[7]  += A1.w * xv;
        acc[8]  += A2.x * xv; acc[9]  += A2.y * xv; acc[10] += A2.z * xv; acc[11] += A2.w * xv;
        acc[12] += A3.x * xv; acc[13] += A3.y * xv; acc[14] += A3.z * xv; acc[15] += A3.w * xv;
    }
    float* o = vpart + ((size_t)(psl * B + b) * KFG) * D + d;
    #pragma unroll
    for (int k = 0; k < KFG; ++k) o[(size_t)k * D] = acc[k];
}

// ---------------- k4: reduce p-splits + LayerNorm ----------------
// grid (16 k, 32 b), block 256; thread owns 3 d's.
__global__ __launch_bounds__(256) void k_ln(const float* __restrict__ vpart,
                                            const float* __restrict__ gamma,
                                            const float* __restrict__ beta,
                                            float* __restrict__ vnorm_out) {
    const int k = blockIdx.x, b = blockIdx.y, t = threadIdx.x;
    const int lane = t & 63, wv = t >> 6;

    float v[3]; float s1 = 0.f, s2 = 0.f;
    #pragma unroll
    for (int j = 0; j < 3; ++j) {
        const int d = t + j * 256;
        float s = 0.f;
        #pragma unroll
        for (int psl = 0; psl < 4; ++psl)
            s += vpart[((size_t)(psl * B + b) * KFG + k) * D + d];
        v[j] = s; s1 += s; s2 += s * s;
    }
    #pragma unroll
    for (int o = 1; o < 64; o <<= 1) {
        s1 += __shfl_xor(s1, o, 64);
        s2 += __shfl_xor(s2, o, 64);
    }
    __shared__ float r1[4], r2[4];
    if (lane == 0) { r1[wv] = s1; r2[wv] = s2; }
    __syncthreads();
    s1 = r1[0] + r1[1] + r1[2] + r1[3];
    s2 = r2[0] + r2[1] + r2[2] + r2[3];

    const float mean = s1 * (1.f / (float)D);
    const float var  = s2 * (1.f / (float)D) - mean * mean;
    const float rs   = rsqrtf(var + LN_EPS);

    #pragma unroll
    for (int j = 0; j < 3; ++j) {
        const int d = t + j * 256;
        float vn = (v[j] - mean) * rs * gamma[d] + beta[d];
        vnorm_out[((size_t)b * KFG + k) * D + d] = vn;
    }
}

// ---------------- k5: classifier partial GEMV over a d-range ----------------
// grid (8 d-splits of 96, 32 b), block 256; thread = class c (c<200 active).
// v_norm slice transposed into LDS once; uniform ds_read_b128 in the loop.
__global__ __launch_bounds__(256) void k_cls(const float* __restrict__ vnorm,
                                             const float* __restrict__ W,
                                             float* __restrict__ lpart) {
    __shared__ float vs_[96 * 16];    // 6 KB, [d_local][k]
    const int dq = blockIdx.x, b = blockIdx.y;
    const int c = threadIdx.x;

    // stage + transpose: read coalesced (96-runs), write strided (one-time cost)
    for (int i = c; i < 96 * 16; i += 256) {
        int k = i / 96, dd = i - k * 96;
        vs_[dd * 16 + k] = vnorm[((size_t)b * KFG + k) * D + dq * 96 + dd];
    }
    __syncthreads();

    const int cc = c < C ? c : (C - 1);     // clamp keeps loads in-bounds
    const float* Wp = W + (size_t)dq * 96 * C + cc;

    float acc[KFG];
    #pragma unroll
    for (int k = 0; k < KFG; ++k) acc[k] = 0.f;

    #pragma unroll 2
    for (int i = 0; i < 96; ++i) {
        float wl = Wp[(size_t)i * C];       // coalesced across lanes
        float4 V0 = *(const float4*)(vs_ + i * 16);
        float4 V1 = *(const float4*)(vs_ + i * 16 + 4);
        float4 V2 = *(const float4*)(vs_ + i * 16 + 8);
        float4 V3 = *(const float4*)(vs_ + i * 16 + 12);
        acc[0]  += V0.x * wl; acc[1]  += V0.y * wl; acc[2]  += V0.z * wl; acc[3]  += V0.w * wl;
        acc[4]  += V1.x * wl; acc[5]  += V1.y * wl; acc[6]  += V1.z * wl; acc[7]  += V1.w * wl;
        acc[8]  += V2.x * wl; acc[9]  += V2.y * wl; acc[10] += V2.z * wl; acc[11] += V2.w * wl;
        acc[12] += V3.x * wl; acc[13] += V3.y * wl; acc[14] += V3.z * wl; acc[15] += V3.w * wl;
    }
    if (c < C) {
        float* o = lpart + ((size_t)(dq * B + b) * KFG) * C + c;
        #pragma unroll
        for (int k = 0; k < KFG; ++k) o[(size_t)k * C] = acc[k];
    }
}

// ---------------- k6: combine d-splits + bias; logits_parts + logits_agg ----------------
__global__ __launch_bounds__(256) void k_comb(const float* __restrict__ lpart,
                                              const float* __restrict__ bcls,
                                              float* __restrict__ parts,
                                              float* __restrict__ agg) {
    const int b = blockIdx.x, c = threadIdx.x;
    if (c >= C) return;
    const float bc = bcls[c];
    float s_agg = 0.f;
    #pragma unroll
    for (int k = 0; k < KFG; ++k) {
        float s = bc;
        #pragma unroll
        for (int dq = 0; dq < 8; ++dq)
            s += lpart[((size_t)(dq * B + b) * KFG + k) * C + c];
        parts[((size_t)b * KFG + k) * C + c] = s;
        s_agg += s;
    }
    agg[(size_t)b * C + c] = s_agg * (1.f / (float)KFG);
}

extern "C" void kernel_launch(void* const* d_in, const int* in_sizes, int n_in,
                              void* d_out, int out_size, void* d_ws, size_t ws_size,
                              hipStream_t stream) {
    const float* x     = (const float*)d_in[0];   // (32,24,24,768)
    const float* proto = (const float*)d_in[1];   // (17,768)
    const float* gamma = (const float*)d_in[2];   // (768)
    const float* beta  = (const float*)d_in[3];   // (768)
    const float* W     = (const float*)d_in[4];   // (768,200)
    const float* bcls  = (const float*)d_in[5];   // (200)

    float* out = (float*)d_out;
    float* A_out     = out;                       // 32*17*576   = 313344
    float* vnorm_out = out + 313344;              // 32*16*768   = 393216
    float* parts_out = out + 706560;              // 32*16*200   = 102400
    float* agg_out   = out + 808960;              // 32*200      = 6400

    float* ws = (float*)d_ws;
    float* psq   = ws;                 // 17            (pad to 32)
    float* xpp   = ws + 32;            // 4*32*17*576   = 1253376
    float* a_ws  = ws + 1253408;       // 32*576*16     = 294912
    float* vpart = ws + 1548320;       // 4*32*16*768   = 1572864
    float* lpart = ws + 3121184;       // 8*32*16*200   = 819200

    hipLaunchKernelGGL(k_psq,     dim3(K1),        dim3(64),  0, stream, proto, psq);
    hipLaunchKernelGGL(k_dots,    dim3(9, 4, B),   dim3(256), 0, stream, x, proto, xpp);
    hipLaunchKernelGGL(k_softmax, dim3(72),        dim3(256), 0, stream, xpp, psq, A_out, a_ws);
    hipLaunchKernelGGL(k_pool,    dim3(3, 4, B),   dim3(256), 0, stream, x, a_ws, vpart);
    hipLaunchKernelGGL(k_ln,      dim3(KFG, B),    dim3(256), 0, stream, vpart, gamma, beta, vnorm_out);
    hipLaunchKernelGGL(k_cls,     dim3(8, B),      dim3(256), 0, stream, vnorm_out, W, lpart);
    hipLaunchKernelGGL(k_comb,    dim3(B),         dim3(256), 0, stream, lpart, bcls, parts_out, agg_out);
}

// Round 3
// 156.010 us; speedup vs baseline: 1.2035x; 1.1504x over previous
//
#include <hip/hip_runtime.h>
#include <hip/hip_bf16.h>

// Problem constants
#define B    32
#define P    576     // 24*24 patches
#define D    768
#define K1   17      // K+1 prototypes
#define KFG  16
#define C    200
#define LN_EPS 1e-6f

#define TPB      32      // patches per k_main block
#define NTILES   18      // 576/32
#define XS_PITCH 776     // bf16 elems/row: 768 + 8 pad (16B-aligned, 2-way-bank-safe)
#define PS_PITCH 776
#define SC_PITCH 20      // fp32 pitch for scores/apool

typedef __attribute__((ext_vector_type(8))) short short8;   // 8 bf16 (4 VGPRs)
typedef __attribute__((ext_vector_type(4))) float f32x4;

__device__ inline unsigned short f2b(float f) {   // fp32 -> bf16 RNE
    union { float f; unsigned u; } x; x.f = f;
    unsigned r = x.u + 0x7FFF + ((x.u >> 16) & 1);
    return (unsigned short)(r >> 16);
}
__device__ inline float b2f(unsigned short u) {   // bf16 -> fp32 exact
    union { unsigned u; float f; } x; x.u = ((unsigned)u) << 16;
    return x.f;
}

// ---------------- k_pre: zero vacc (blocks 0..383) + psq (blocks 384..400) ----------------
__global__ __launch_bounds__(256) void k_pre(const float* __restrict__ proto,
                                             float* __restrict__ psq,
                                             float* __restrict__ vacc) {
    const int blk = blockIdx.x, t = threadIdx.x;
    if (blk < 384) {
        f32x4 z = {0.f, 0.f, 0.f, 0.f};
        ((f32x4*)vacc)[blk * 256 + t] = z;          // 384*256*4 = 393216 floats
        return;
    }
    const int k = blk - 384;                        // 0..16
    float a0 = proto[k * D + t], a1 = proto[k * D + t + 256], a2 = proto[k * D + t + 512];
    float s = a0 * a0 + a1 * a1 + a2 * a2;
    #pragma unroll
    for (int o = 1; o < 64; o <<= 1) s += __shfl_xor(s, o, 64);
    __shared__ float r[4];
    if ((t & 63) == 0) r[t >> 6] = s;
    __syncthreads();
    if (t == 0) psq[k] = r[0] + r[1] + r[2] + r[3];
}

// ---------------- k_main: fused dots (bf16 MFMA) + softmax + pooling ----------------
// grid (18 tiles, 32 b), block 256 (4 waves). LDS 78.6 KB -> 2 blocks/CU.
// Reads x ONCE (56.6 MB total). Writes A_out + atomic-accumulates vacc.
__global__ __launch_bounds__(256) void k_main(const float* __restrict__ x,
                                              const float* __restrict__ proto,
                                              const float* __restrict__ psq,
                                              float* __restrict__ A_out,
                                              float* __restrict__ vacc) {
    __shared__ __align__(16) unsigned char smem[78608];
    unsigned short* xs = (unsigned short*)smem;                    // [32][776] bf16
    unsigned short* ps = (unsigned short*)(smem + 49664);          // [17][776] bf16
    float* scores = (float*)(smem + 49664);                        // [32][20] fp32 (alias ps)
    float* apool  = (float*)(smem + 76048);                        // [32][20] fp32

    const int tile = blockIdx.x, b = blockIdx.y;
    const int t = threadIdx.x;
    const int wv = t >> 6, lane = t & 63;
    const int p0 = tile * TPB;

    // ---- stage x: 32 patches x 768 fp32 -> bf16 LDS (coalesced float4 loads) ----
    {
        const int pl = t >> 3, seg = t & 7;        // 8 threads/patch, 96 floats each
        const float* src = x + ((size_t)(b * P + p0 + pl)) * D + seg * 96;
        unsigned short* dst = xs + pl * XS_PITCH + seg * 96;
        #pragma unroll
        for (int i = 0; i < 12; ++i) {
            float4 v0 = *(const float4*)(src + i * 8);
            float4 v1 = *(const float4*)(src + i * 8 + 4);
            short8 w;
            w[0] = (short)f2b(v0.x); w[1] = (short)f2b(v0.y);
            w[2] = (short)f2b(v0.z); w[3] = (short)f2b(v0.w);
            w[4] = (short)f2b(v1.x); w[5] = (short)f2b(v1.y);
            w[6] = (short)f2b(v1.z); w[7] = (short)f2b(v1.w);
            *(short8*)(dst + i * 8) = w;
        }
    }
    // ---- stage protos: 17 x 768 fp32 -> bf16 LDS ----
    for (int i = t; i < 17 * 96; i += 256) {
        const int row = i / 96, ch = i - row * 96;
        const float* sp = proto + row * D + ch * 8;
        float4 v0 = *(const float4*)(sp);
        float4 v1 = *(const float4*)(sp + 4);
        short8 w;
        w[0] = (short)f2b(v0.x); w[1] = (short)f2b(v0.y);
        w[2] = (short)f2b(v0.z); w[3] = (short)f2b(v0.w);
        w[4] = (short)f2b(v1.x); w[5] = (short)f2b(v1.y);
        w[6] = (short)f2b(v1.z); w[7] = (short)f2b(v1.w);
        *(short8*)(ps + row * PS_PITCH + ch * 8) = w;
    }
    __syncthreads();

    // ---- dots via MFMA: waves 0,1 each own a 16-patch M-tile ----
    // acc0: protos 0..15 (B-frag: lane n=lane&15 reads proto n's row -> B[k][n])
    // acc1: proto 16 broadcast-B (all lanes read row 16 -> D[p][n]=dot(x_p,p16) for all n)
    f32x4 acc0 = {0.f, 0.f, 0.f, 0.f}, acc1 = {0.f, 0.f, 0.f, 0.f};
    if (wv < 2) {
        const int kq = (lane >> 4) * 8;
        const unsigned short* arow = xs + (wv * 16 + (lane & 15)) * XS_PITCH + kq;
        const unsigned short* brow = ps + (lane & 15) * PS_PITCH + kq;
        const unsigned short* b16  = ps + 16 * PS_PITCH + kq;
        #pragma unroll 4
        for (int k0 = 0; k0 < D; k0 += 32) {
            short8 A  = *(const short8*)(arow + k0);
            short8 Bv = *(const short8*)(brow + k0);
            short8 B6 = *(const short8*)(b16 + k0);
            acc0 = __builtin_amdgcn_mfma_f32_16x16x32_bf16(A, Bv, acc0, 0, 0, 0);
            acc1 = __builtin_amdgcn_mfma_f32_16x16x32_bf16(A, B6, acc1, 0, 0, 0);
        }
    }
    __syncthreads();     // all ps B-frag reads done before scores alias-write

    if (wv < 2) {
        const int prow = wv * 16 + (lane >> 4) * 4;
        #pragma unroll
        for (int r = 0; r < 4; ++r) {
            scores[(prow + r) * SC_PITCH + (lane & 15)] = acc0[r];
            if ((lane & 15) == 0) scores[(prow + r) * SC_PITCH + 16] = acc1[r];
        }
    }
    __syncthreads();

    // ---- softmax (wave 0, lane = patch) ----
    if (wv == 0) {
        const int pp = lane & 31;
        float l[K1];
        #pragma unroll
        for (int k = 0; k < K1; ++k)
            l[k] = 2.f * scores[pp * SC_PITCH + k] - psq[k];   // x_sq cancels
        float m = l[0];
        #pragma unroll
        for (int k = 1; k < K1; ++k) m = fmaxf(m, l[k]);
        float e[K1]; float sum = 0.f;
        #pragma unroll
        for (int k = 0; k < K1; ++k) { e[k] = __expf(l[k] - m); sum += e[k]; }
        const float inv = 1.f / sum;
        const float invP = inv * (1.f / (float)P);
        if (lane < 32) {
            #pragma unroll
            for (int k = 0; k < K1; ++k)
                A_out[((size_t)b * K1 + k) * P + p0 + pp] = e[k] * inv;
            #pragma unroll
            for (int k = 0; k < KFG; ++k)
                apool[pp * SC_PITCH + k] = e[k] * invP;
        }
    }
    __syncthreads();

    // ---- pooling: thread owns d = t, t+256, t+512; loop 32 patches ----
    float accp[3][KFG];
    #pragma unroll
    for (int j = 0; j < 3; ++j)
        #pragma unroll
        for (int k = 0; k < KFG; ++k) accp[j][k] = 0.f;

    for (int p = 0; p < TPB; ++p) {
        const f32x4* ar = (const f32x4*)(apool + p * SC_PITCH);   // uniform -> broadcast
        f32x4 A0 = ar[0], A1 = ar[1], A2 = ar[2], A3 = ar[3];
        float a_[KFG] = { A0[0],A0[1],A0[2],A0[3], A1[0],A1[1],A1[2],A1[3],
                          A2[0],A2[1],A2[2],A2[3], A3[0],A3[1],A3[2],A3[3] };
        #pragma unroll
        for (int j = 0; j < 3; ++j) {
            float xv = b2f(xs[p * XS_PITCH + t + j * 256]);
            #pragma unroll
            for (int k = 0; k < KFG; ++k) accp[j][k] += a_[k] * xv;
        }
    }
    float* vb = vacc + ((size_t)b * KFG) * D;
    #pragma unroll
    for (int j = 0; j < 3; ++j)
        #pragma unroll
        for (int k = 0; k < KFG; ++k)
            atomicAdd(vb + (size_t)k * D + t + j * 256, accp[j][k]);
}

// ---------------- k_ln: LayerNorm over vacc rows ----------------
// grid (16 k, 32 b), block 256; thread owns 3 d's.
__global__ __launch_bounds__(256) void k_ln(const float* __restrict__ vacc,
                                            const float* __restrict__ gamma,
                                            const float* __restrict__ beta,
                                            float* __restrict__ vnorm_out) {
    const int k = blockIdx.x, b = blockIdx.y, t = threadIdx.x;
    const int lane = t & 63, wv = t >> 6;

    float v[3]; float s1 = 0.f, s2 = 0.f;
    #pragma unroll
    for (int j = 0; j < 3; ++j) {
        const int d = t + j * 256;
        float s = vacc[((size_t)b * KFG + k) * D + d];
        v[j] = s; s1 += s; s2 += s * s;
    }
    #pragma unroll
    for (int o = 1; o < 64; o <<= 1) {
        s1 += __shfl_xor(s1, o, 64);
        s2 += __shfl_xor(s2, o, 64);
    }
    __shared__ float r1[4], r2[4];
    if (lane == 0) { r1[wv] = s1; r2[wv] = s2; }
    __syncthreads();
    s1 = r1[0] + r1[1] + r1[2] + r1[3];
    s2 = r2[0] + r2[1] + r2[2] + r2[3];

    const float mean = s1 * (1.f / (float)D);
    const float var  = s2 * (1.f / (float)D) - mean * mean;
    const float rs   = rsqrtf(var + LN_EPS);

    #pragma unroll
    for (int j = 0; j < 3; ++j) {
        const int d = t + j * 256;
        float vn = (v[j] - mean) * rs * gamma[d] + beta[d];
        vnorm_out[((size_t)b * KFG + k) * D + d] = vn;
    }
}

// ---------------- k_cls: classifier partial GEMV over a d-range ----------------
// grid (8 d-splits of 96, 32 b), block 256; thread = class c.
__global__ __launch_bounds__(256) void k_cls(const float* __restrict__ vnorm,
                                             const float* __restrict__ W,
                                             float* __restrict__ lpart) {
    __shared__ float vs_[96 * 16];    // [d_local][k]
    const int dq = blockIdx.x, b = blockIdx.y;
    const int c = threadIdx.x;

    for (int i = c; i < 96 * 16; i += 256) {
        int k = i / 96, dd = i - k * 96;
        vs_[dd * 16 + k] = vnorm[((size_t)b * KFG + k) * D + dq * 96 + dd];
    }
    __syncthreads();

    const int cc = c < C ? c : (C - 1);
    const float* Wp = W + (size_t)dq * 96 * C + cc;

    float acc[KFG];
    #pragma unroll
    for (int k = 0; k < KFG; ++k) acc[k] = 0.f;

    #pragma unroll 2
    for (int i = 0; i < 96; ++i) {
        float wl = Wp[(size_t)i * C];
        float4 V0 = *(const float4*)(vs_ + i * 16);
        float4 V1 = *(const float4*)(vs_ + i * 16 + 4);
        float4 V2 = *(const float4*)(vs_ + i * 16 + 8);
        float4 V3 = *(const float4*)(vs_ + i * 16 + 12);
        acc[0]  += V0.x * wl; acc[1]  += V0.y * wl; acc[2]  += V0.z * wl; acc[3]  += V0.w * wl;
        acc[4]  += V1.x * wl; acc[5]  += V1.y * wl; acc[6]  += V1.z * wl; acc[7]  += V1.w * wl;
        acc[8]  += V2.x * wl; acc[9]  += V2.y * wl; acc[10] += V2.z * wl; acc[11] += V2.w * wl;
        acc[12] += V3.x * wl; acc[13] += V3.y * wl; acc[14] += V3.z * wl; acc[15] += V3.w * wl;
    }
    if (c < C) {
        float* o = lpart + ((size_t)(dq * B + b) * KFG) * C + c;
        #pragma unroll
        for (int k = 0; k < KFG; ++k) o[(size_t)k * C] = acc[k];
    }
}

// ---------------- k_comb: combine d-splits + bias; logits_parts + logits_agg ----------------
__global__ __launch_bounds__(256) void k_comb(const float* __restrict__ lpart,
                                              const float* __restrict__ bcls,
                                              float* __restrict__ parts,
                                              float* __restrict__ agg) {
    const int b = blockIdx.x, c = threadIdx.x;
    if (c >= C) return;
    const float bc = bcls[c];
    float s_agg = 0.f;
    #pragma unroll
    for (int k = 0; k < KFG; ++k) {
        float s = bc;
        #pragma unroll
        for (int dq = 0; dq < 8; ++dq)
            s += lpart[((size_t)(dq * B + b) * KFG + k) * C + c];
        parts[((size_t)b * KFG + k) * C + c] = s;
        s_agg += s;
    }
    agg[(size_t)b * C + c] = s_agg * (1.f / (float)KFG);
}

extern "C" void kernel_launch(void* const* d_in, const int* in_sizes, int n_in,
                              void* d_out, int out_size, void* d_ws, size_t ws_size,
                              hipStream_t stream) {
    const float* x     = (const float*)d_in[0];   // (32,24,24,768)
    const float* proto = (const float*)d_in[1];   // (17,768)
    const float* gamma = (const float*)d_in[2];   // (768)
    const float* beta  = (const float*)d_in[3];   // (768)
    const float* W     = (const float*)d_in[4];   // (768,200)
    const float* bcls  = (const float*)d_in[5];   // (200)

    float* out = (float*)d_out;
    float* A_out     = out;                       // 32*17*576   = 313344
    float* vnorm_out = out + 313344;              // 32*16*768   = 393216
    float* parts_out = out + 706560;              // 32*16*200   = 102400
    float* agg_out   = out + 808960;              // 32*200      = 6400

    float* ws = (float*)d_ws;
    float* psq  = ws;                  // 17 (pad 32)
    float* vacc = ws + 32;             // 32*16*768 = 393216
    float* lpart = ws + 393248;        // 8*32*16*200 = 819200

    hipLaunchKernelGGL(k_pre,  dim3(401),        dim3(256), 0, stream, proto, psq, vacc);
    hipLaunchKernelGGL(k_main, dim3(NTILES, B),  dim3(256), 0, stream, x, proto, psq, A_out, vacc);
    hipLaunchKernelGGL(k_ln,   dim3(KFG, B),     dim3(256), 0, stream, vacc, gamma, beta, vnorm_out);
    hipLaunchKernelGGL(k_cls,  dim3(8, B),       dim3(256), 0, stream, vnorm_out, W, lpart);
    hipLaunchKernelGGL(k_comb, dim3(B),          dim3(256), 0, stream, lpart, bcls, parts_out, agg_out);
}